// Round 1
// baseline (387.599 us; speedup 1.0000x reference)
//
#include <hip/hip_runtime.h>
#include <hip/hip_bf16.h>

// B=4, S=2048, D=1024, H=16, DH=64
typedef __attribute__((ext_vector_type(4))) float f32x4;
typedef __attribute__((ext_vector_type(8))) short bf16x8;
typedef __attribute__((ext_vector_type(4))) unsigned short u16x4;

#define MFMA16(a, b, c) __builtin_amdgcn_mfma_f32_16x16x32_bf16((a), (b), (c), 0, 0, 0)

static __device__ __forceinline__ unsigned short f2bf(float f) {
    unsigned u = __float_as_uint(f);
    u += 0x7FFFu + ((u >> 16) & 1u);   // RNE
    return (unsigned short)(u >> 16);
}

// ---------------- Q projection: q = x @ Wq^T, output bf16 [B,H,S,DH] ----------------
__global__ __launch_bounds__(256) void qproj_kernel(const float* __restrict__ x,
                                                    const float* __restrict__ wq,
                                                    unsigned short* __restrict__ qout) {
    __shared__ __align__(16) unsigned short As[128][40];  // pad 32->40: 80B stride, 16B-aligned
    __shared__ __align__(16) unsigned short Bs[128][40];
    const int m0 = blockIdx.x * 128;
    const int n0 = blockIdx.y * 128;
    const int tid = threadIdx.x;
    const int wave = tid >> 6, lane = tid & 63;
    const int lg = lane >> 4, lc = lane & 15;
    const int wm = wave >> 1, wn = wave & 1;   // 2x2 wave grid, 64x64 per wave

    f32x4 acc[4][4];
#pragma unroll
    for (int i = 0; i < 4; ++i)
#pragma unroll
        for (int j = 0; j < 4; ++j) acc[i][j] = (f32x4){0.f, 0.f, 0.f, 0.f};

    for (int ks = 0; ks < 1024; ks += 32) {
#pragma unroll
        for (int i = 0; i < 4; ++i) {
            int c = tid + i * 256;            // 0..1023 float4-chunks
            int row = c >> 3, kc = (c & 7) * 4;
            float4 av = *(const float4*)(x + (size_t)(m0 + row) * 1024 + ks + kc);
            u16x4 ab = { f2bf(av.x), f2bf(av.y), f2bf(av.z), f2bf(av.w) };
            *(u16x4*)&As[row][kc] = ab;
            float4 bv = *(const float4*)(wq + (size_t)(n0 + row) * 1024 + ks + kc);
            u16x4 bb = { f2bf(bv.x), f2bf(bv.y), f2bf(bv.z), f2bf(bv.w) };
            *(u16x4*)&Bs[row][kc] = bb;
        }
        __syncthreads();
        bf16x8 af[4], bfr[4];
#pragma unroll
        for (int i = 0; i < 4; ++i) {
            af[i]  = *(const bf16x8*)&As[wm * 64 + i * 16 + lc][lg * 8];
            bfr[i] = *(const bf16x8*)&Bs[wn * 64 + i * 16 + lc][lg * 8];
        }
#pragma unroll
        for (int mi = 0; mi < 4; ++mi)
#pragma unroll
            for (int ni = 0; ni < 4; ++ni)
                acc[mi][ni] = MFMA16(af[mi], bfr[ni], acc[mi][ni]);
        __syncthreads();
    }
    // store q bf16 into [B,H,S,DH]; D row=lg*4+reg, col=lc
#pragma unroll
    for (int mi = 0; mi < 4; ++mi)
#pragma unroll
        for (int ni = 0; ni < 4; ++ni)
#pragma unroll
            for (int r = 0; r < 4; ++r) {
                int m = m0 + wm * 64 + mi * 16 + lg * 4 + r;
                int n = n0 + wn * 64 + ni * 16 + lc;
                int b = m >> 11, s = m & 2047;
                int h = n >> 6, dh = n & 63;
                qout[(((size_t)b * 16 + h) * 2048 + s) * 64 + dh] = f2bf(acc[mi][ni][r]);
            }
}

// ---------------- k fp32 -> bf16 (same layout) ----------------
__global__ void conv_bf16_kernel(const float* __restrict__ in, unsigned short* __restrict__ outp, int n4) {
    int i = blockIdx.x * blockDim.x + threadIdx.x;
    if (i < n4) {
        float4 v = ((const float4*)in)[i];
        u16x4 o = { f2bf(v.x), f2bf(v.y), f2bf(v.z), f2bf(v.w) };
        ((u16x4*)outp)[i] = o;
    }
}

// ---------------- v fp32 [B,H,S,DH] -> bf16 transposed [B,H,DH,S] ----------------
__global__ __launch_bounds__(256) void vtrans_kernel(const float* __restrict__ v, unsigned short* __restrict__ vt) {
    __shared__ float buf[64][65];
    const int s0 = blockIdx.x * 64;
    const int bh = blockIdx.y;
    const int tid = threadIdx.x;
#pragma unroll
    for (int i = 0; i < 4; ++i) {
        int c = tid + i * 256;             // 0..1023 float4-chunks of the 64x64 tile
        int s = c >> 4, dc = (c & 15) * 4;
        float4 val = *(const float4*)(v + ((size_t)bh * 2048 + s0 + s) * 64 + dc);
        buf[s][dc] = val.x; buf[s][dc + 1] = val.y; buf[s][dc + 2] = val.z; buf[s][dc + 3] = val.w;
    }
    __syncthreads();
#pragma unroll
    for (int i = 0; i < 4; ++i) {
        int c = tid + i * 256;
        int dh = c >> 4, sc = (c & 15) * 4;
        u16x4 o = { f2bf(buf[sc][dh]), f2bf(buf[sc + 1][dh]), f2bf(buf[sc + 2][dh]), f2bf(buf[sc + 3][dh]) };
        *(u16x4*)(vt + ((size_t)bh * 64 + dh) * 2048 + s0 + sc) = o;
    }
}

// ---------------- fused causal flash attention + residual ----------------
// grid: (S/64, B*H); 4 waves, each owns 16 q-rows. KV-block = 32.
__global__ __launch_bounds__(256) void attn_kernel(const unsigned short* __restrict__ qg,
                                                   const unsigned short* __restrict__ kg,
                                                   const unsigned short* __restrict__ vtg,
                                                   const float* __restrict__ x,
                                                   float* __restrict__ outp) {
    __shared__ __align__(16) unsigned short Ks[32][72];    // [key][dh], stride 144B
    __shared__ __align__(16) unsigned short VTs[64][40];   // [dh][key], stride 80B
    __shared__ __align__(16) unsigned short Ps[4][16][40]; // per-wave P re-layout buffer

    const int qb = blockIdx.x;
    const int bh = blockIdx.y;
    const int b = bh >> 4, h = bh & 15;
    const int tid = threadIdx.x;
    const int wave = tid >> 6, lane = tid & 63;
    const int lg = lane >> 4, lc = lane & 15;
    const int qr0 = qb * 64 + wave * 16;

    // Q A-frags held in registers: row = lc, k = lg*8 + j (+32 per chunk)
    const unsigned short* qptr = qg + ((size_t)bh * 2048 + qr0 + lc) * 64;
    bf16x8 qf[2];
    qf[0] = *(const bf16x8*)(qptr + lg * 8);
    qf[1] = *(const bf16x8*)(qptr + 32 + lg * 8);

    f32x4 oacc[4];
#pragma unroll
    for (int t = 0; t < 4; ++t) oacc[t] = (f32x4){0.f, 0.f, 0.f, 0.f};
    float m_r[4] = {-1e30f, -1e30f, -1e30f, -1e30f};
    float l_r[4] = {0.f, 0.f, 0.f, 0.f};

    const int nkv = 2 * qb + 2;
    for (int kv = 0; kv < nkv; ++kv) {
        {   // stage K tile [32][64] and V^T tile [64][32], bf16, 16B per thread each
            int key = tid >> 3;
            int kc = (tid & 7) * 8;
            *(bf16x8*)&Ks[key][kc] =
                *(const bf16x8*)(kg + ((size_t)bh * 2048 + kv * 32 + key) * 64 + kc);
            int dh = tid >> 2;
            int kc2 = (tid & 3) * 8;
            *(bf16x8*)&VTs[dh][kc2] =
                *(const bf16x8*)(vtg + ((size_t)bh * 64 + dh) * 2048 + kv * 32 + kc2);
        }
        __syncthreads();

        // S = Q K^T : B-frag col=lc(+16t) is a K row; k-contig read
        f32x4 sacc[2] = {(f32x4){0.f,0.f,0.f,0.f}, (f32x4){0.f,0.f,0.f,0.f}};
#pragma unroll
        for (int c = 0; c < 2; ++c) {
            bf16x8 kf0 = *(const bf16x8*)&Ks[lc][32 * c + lg * 8];
            bf16x8 kf1 = *(const bf16x8*)&Ks[lc + 16][32 * c + lg * 8];
            sacc[0] = MFMA16(qf[c], kf0, sacc[0]);
            sacc[1] = MFMA16(qf[c], kf1, sacc[1]);
        }

        // scale by 1/sqrt(D)=1/32, causal mask
        float pv[2][4];
#pragma unroll
        for (int t = 0; t < 2; ++t)
#pragma unroll
            for (int r = 0; r < 4; ++r) {
                float sv = sacc[t][r] * 0.03125f;
                int kgi = kv * 32 + lc + 16 * t;
                int qgi = qr0 + lg * 4 + r;
                pv[t][r] = (kgi > qgi) ? -1e30f : sv;
            }

        // online softmax, rows live across 16-lane groups
#pragma unroll
        for (int r = 0; r < 4; ++r) {
            float mx = fmaxf(pv[0][r], pv[1][r]);
#pragma unroll
            for (int m = 1; m < 16; m <<= 1) mx = fmaxf(mx, __shfl_xor(mx, m, 64));
            float mnew = fmaxf(m_r[r], mx);
            float corr = __expf(m_r[r] - mnew);
            float p0 = __expf(pv[0][r] - mnew);
            float p1 = __expf(pv[1][r] - mnew);
            float rs = p0 + p1;
#pragma unroll
            for (int m = 1; m < 16; m <<= 1) rs += __shfl_xor(rs, m, 64);
            m_r[r] = mnew;
            l_r[r] = l_r[r] * corr + rs;
#pragma unroll
            for (int t = 0; t < 4; ++t) oacc[t][r] *= corr;
            pv[0][r] = p0; pv[1][r] = p1;
        }

        // P (C-layout) -> LDS -> A-layout frag for PV
#pragma unroll
        for (int t = 0; t < 2; ++t)
#pragma unroll
            for (int r = 0; r < 4; ++r)
                Ps[wave][lg * 4 + r][lc + 16 * t] = f2bf(pv[t][r]);
        asm volatile("s_waitcnt lgkmcnt(0)" ::: "memory");
        bf16x8 pf = *(const bf16x8*)&Ps[wave][lc][lg * 8];
#pragma unroll
        for (int t = 0; t < 4; ++t) {
            bf16x8 vf = *(const bf16x8*)&VTs[lc + 16 * t][lg * 8];
            oacc[t] = MFMA16(pf, vf, oacc[t]);
        }
        __syncthreads();
    }

    float inv_l[4];
#pragma unroll
    for (int r = 0; r < 4; ++r) inv_l[r] = 1.0f / l_r[r];
#pragma unroll
    for (int t = 0; t < 4; ++t)
#pragma unroll
        for (int r = 0; r < 4; ++r) {
            int qgi = qr0 + lg * 4 + r;
            int dh = lc + 16 * t;
            size_t oi = ((size_t)b * 2048 + qgi) * 1024 + (size_t)h * 64 + dh;
            outp[oi] = x[oi] + oacc[t][r] * inv_l[r];
        }
}

extern "C" void kernel_launch(void* const* d_in, const int* in_sizes, int n_in,
                              void* d_out, int out_size, void* d_ws, size_t ws_size,
                              hipStream_t stream) {
    const float* x  = (const float*)d_in[0];
    const float* k  = (const float*)d_in[1];
    const float* v  = (const float*)d_in[2];
    const float* wq = (const float*)d_in[3];
    float* outp = (float*)d_out;

    const size_t NELEM = (size_t)4 * 2048 * 1024;  // 8,388,608 per tensor
    unsigned short* qb  = (unsigned short*)d_ws;
    unsigned short* kb  = qb + NELEM;
    unsigned short* vtb = kb + NELEM;

    qproj_kernel<<<dim3(64, 8), 256, 0, stream>>>(x, wq, qb);
    conv_bf16_kernel<<<(int)(NELEM / 4 / 256), 256, 0, stream>>>(k, kb, (int)(NELEM / 4));
    vtrans_kernel<<<dim3(32, 64), 256, 0, stream>>>(v, vtb);
    attn_kernel<<<dim3(32, 64), 256, 0, stream>>>(qb, kb, vtb, x, outp);
}

// Round 2
// 220.157 us; speedup vs baseline: 1.7606x; 1.7606x over previous
//
#include <hip/hip_runtime.h>
#include <hip/hip_bf16.h>

// B=4, S=2048, D=1024, H=16, DH=64
typedef __attribute__((ext_vector_type(4))) float f32x4;
typedef __attribute__((ext_vector_type(8))) short bf16x8;
typedef __attribute__((ext_vector_type(4))) unsigned short u16x4;

#define MFMA16(a, b, c) __builtin_amdgcn_mfma_f32_16x16x32_bf16((a), (b), (c), 0, 0, 0)

static __device__ __forceinline__ unsigned short f2bf(float f) {
    unsigned u = __float_as_uint(f);
    u += 0x7FFFu + ((u >> 16) & 1u);   // RNE
    return (unsigned short)(u >> 16);
}

// ---------------- Q projection: q = x @ Wq^T, output bf16 [B,H,S,DH] ----------------
__global__ __launch_bounds__(256) void qproj_kernel(const float* __restrict__ x,
                                                    const float* __restrict__ wq,
                                                    unsigned short* __restrict__ qout) {
    __shared__ __align__(16) unsigned short As[128][40];
    __shared__ __align__(16) unsigned short Bs[128][40];
    const int m0 = blockIdx.x * 128;
    const int n0 = blockIdx.y * 128;
    const int tid = threadIdx.x;
    const int wave = tid >> 6, lane = tid & 63;
    const int lg = lane >> 4, lc = lane & 15;
    const int wm = wave >> 1, wn = wave & 1;

    f32x4 acc[4][4];
#pragma unroll
    for (int i = 0; i < 4; ++i)
#pragma unroll
        for (int j = 0; j < 4; ++j) acc[i][j] = (f32x4){0.f, 0.f, 0.f, 0.f};

    for (int ks = 0; ks < 1024; ks += 32) {
#pragma unroll
        for (int i = 0; i < 4; ++i) {
            int c = tid + i * 256;
            int row = c >> 3, kc = (c & 7) * 4;
            float4 av = *(const float4*)(x + (size_t)(m0 + row) * 1024 + ks + kc);
            u16x4 ab = { f2bf(av.x), f2bf(av.y), f2bf(av.z), f2bf(av.w) };
            *(u16x4*)&As[row][kc] = ab;
            float4 bv = *(const float4*)(wq + (size_t)(n0 + row) * 1024 + ks + kc);
            u16x4 bb = { f2bf(bv.x), f2bf(bv.y), f2bf(bv.z), f2bf(bv.w) };
            *(u16x4*)&Bs[row][kc] = bb;
        }
        __syncthreads();
        bf16x8 af[4], bfr[4];
#pragma unroll
        for (int i = 0; i < 4; ++i) {
            af[i]  = *(const bf16x8*)&As[wm * 64 + i * 16 + lc][lg * 8];
            bfr[i] = *(const bf16x8*)&Bs[wn * 64 + i * 16 + lc][lg * 8];
        }
#pragma unroll
        for (int mi = 0; mi < 4; ++mi)
#pragma unroll
            for (int ni = 0; ni < 4; ++ni)
                acc[mi][ni] = MFMA16(af[mi], bfr[ni], acc[mi][ni]);
        __syncthreads();
    }
#pragma unroll
    for (int mi = 0; mi < 4; ++mi)
#pragma unroll
        for (int ni = 0; ni < 4; ++ni)
#pragma unroll
            for (int r = 0; r < 4; ++r) {
                int m = m0 + wm * 64 + mi * 16 + lg * 4 + r;
                int n = n0 + wn * 64 + ni * 16 + lc;
                int b = m >> 11, s = m & 2047;
                int h = n >> 6, dh = n & 63;
                qout[(((size_t)b * 16 + h) * 2048 + s) * 64 + dh] = f2bf(acc[mi][ni][r]);
            }
}

// ---------------- k fp32 -> bf16 (same layout) ----------------
__global__ void conv_bf16_kernel(const float* __restrict__ in, unsigned short* __restrict__ outp, int n4) {
    int i = blockIdx.x * blockDim.x + threadIdx.x;
    if (i < n4) {
        float4 v = ((const float4*)in)[i];
        u16x4 o = { f2bf(v.x), f2bf(v.y), f2bf(v.z), f2bf(v.w) };
        ((u16x4*)outp)[i] = o;
    }
}

// ---------------- v fp32 [B,H,S,DH] -> bf16 transposed [B,H,DH,S] ----------------
__global__ __launch_bounds__(256) void vtrans_kernel(const float* __restrict__ v, unsigned short* __restrict__ vt) {
    __shared__ float buf[64][65];
    const int s0 = blockIdx.x * 64;
    const int bh = blockIdx.y;
    const int tid = threadIdx.x;
#pragma unroll
    for (int i = 0; i < 4; ++i) {
        int c = tid + i * 256;
        int s = c >> 4, dc = (c & 15) * 4;
        float4 val = *(const float4*)(v + ((size_t)bh * 2048 + s0 + s) * 64 + dc);
        buf[s][dc] = val.x; buf[s][dc + 1] = val.y; buf[s][dc + 2] = val.z; buf[s][dc + 3] = val.w;
    }
    __syncthreads();
#pragma unroll
    for (int i = 0; i < 4; ++i) {
        int c = tid + i * 256;
        int dh = c >> 4, sc = (c & 15) * 4;
        u16x4 o = { f2bf(buf[sc][dh]), f2bf(buf[sc + 1][dh]), f2bf(buf[sc + 2][dh]), f2bf(buf[sc + 3][dh]) };
        *(u16x4*)(vt + ((size_t)bh * 64 + dh) * 2048 + s0 + sc) = o;
    }
}

// ---------------- fused causal flash attention + residual ----------------
// grid: (S/128, B*H); 4 waves, each owns 32 q-rows (2 x 16-row tiles). KVBLK=64.
// Swapped QK^T (S^T = K Q^T): D col = q-row, row = k  -> softmax mostly in-lane.
// K/VT LDS tiles unpadded [64][64] with 16B-chunk XOR swizzle (chunk ^= row&7).
__global__ __launch_bounds__(256) void attn_kernel(const unsigned short* __restrict__ qg,
                                                   const unsigned short* __restrict__ kg,
                                                   const unsigned short* __restrict__ vtg,
                                                   const float* __restrict__ x,
                                                   float* __restrict__ outp) {
    __shared__ __align__(16) unsigned short Ks[2][64][64];
    __shared__ __align__(16) unsigned short VTs[2][64][64];
    __shared__ __align__(16) unsigned short Ps[4][32][72];

    const int qb = blockIdx.x;
    const int bh = blockIdx.y;
    const int b = bh >> 4, h = bh & 15;
    const int tid = threadIdx.x;
    const int wave = tid >> 6, lane = tid & 63;
    const int lg = lane >> 4, lc = lane & 15;
    const int qw0 = qb * 128 + wave * 32;
    const int lc7 = lc & 7;

    // staging coords: thread -> row (0..63), two 8-elem chunks at (tid&3)*16
    const int srow = tid >> 2;
    const int scb  = (tid & 3) * 16;
    const int c16a = (tid & 3) * 2;
    const int swz_a = (c16a ^ (srow & 7)) * 8;
    const int swz_b = ((c16a + 1) ^ (srow & 7)) * 8;
    const unsigned short* kbase = kg  + ((size_t)bh * 2048 + srow) * 64 + scb;
    const unsigned short* vbase = vtg + ((size_t)bh * 64 + srow) * 2048 + scb;

    // Q A/B frags in registers: qf[qt][c] = Q[qw0+qt*16+lc][c*32 + lg*8 ..]
    bf16x8 qf[2][2];
#pragma unroll
    for (int qt = 0; qt < 2; ++qt)
#pragma unroll
        for (int c = 0; c < 2; ++c)
            qf[qt][c] = *(const bf16x8*)(qg + ((size_t)bh * 2048 + qw0 + qt * 16 + lc) * 64 + c * 32 + lg * 8);

    f32x4 oacc[2][4];
#pragma unroll
    for (int qt = 0; qt < 2; ++qt)
#pragma unroll
        for (int dt = 0; dt < 4; ++dt) oacc[qt][dt] = (f32x4){0.f, 0.f, 0.f, 0.f};
    float m_r[2] = {-1e30f, -1e30f};
    float l_r[2] = {0.f, 0.f};

    const int nkv = 2 * qb + 2;

    // prologue: stage tile 0 into buffer 0
    {
        bf16x8 k0 = *(const bf16x8*)(kbase);
        bf16x8 k1 = *(const bf16x8*)(kbase + 8);
        bf16x8 v0 = *(const bf16x8*)(vbase);
        bf16x8 v1 = *(const bf16x8*)(vbase + 8);
        *(bf16x8*)&Ks[0][srow][swz_a]  = k0;
        *(bf16x8*)&Ks[0][srow][swz_b]  = k1;
        *(bf16x8*)&VTs[0][srow][swz_a] = v0;
        *(bf16x8*)&VTs[0][srow][swz_b] = v1;
    }

    int cur = 0;
    for (int kv = 0; kv < nkv; ++kv) {
        __syncthreads();   // staged writes for buf[cur] visible; prev readers of buf[cur^1] done

        // issue next-tile global loads (latency hides under compute)
        const bool havenext = (kv + 1 < nkv);
        const int nxt = havenext ? kv + 1 : kv;
        bf16x8 nk0 = *(const bf16x8*)(kbase + (size_t)nxt * 4096);
        bf16x8 nk1 = *(const bf16x8*)(kbase + (size_t)nxt * 4096 + 8);
        bf16x8 nv0 = *(const bf16x8*)(vbase + nxt * 64);
        bf16x8 nv1 = *(const bf16x8*)(vbase + nxt * 64 + 8);

        const bool active = (kv * 64 <= qw0 + 31);
        if (active) {
            // ---- S^T = K Q^T : 16 MFMA ----
            bf16x8 kf[4][2];
#pragma unroll
            for (int kt = 0; kt < 4; ++kt)
#pragma unroll
                for (int c = 0; c < 2; ++c)
                    kf[kt][c] = *(const bf16x8*)&Ks[cur][kt * 16 + lc][((4 * c + lg) ^ lc7) * 8];

            f32x4 st[2][4];
#pragma unroll
            for (int qt = 0; qt < 2; ++qt)
#pragma unroll
                for (int kt = 0; kt < 4; ++kt) {
                    f32x4 a = (f32x4){0.f, 0.f, 0.f, 0.f};
                    a = MFMA16(kf[kt][0], qf[qt][0], a);
                    a = MFMA16(kf[kt][1], qf[qt][1], a);
                    st[qt][kt] = a;
                }

            const int kvb = kv * 64;
            // ---- softmax (per q-tile; q-row = qw0 + qt*16 + lc, scores in-lane) ----
#pragma unroll
            for (int qt = 0; qt < 2; ++qt) {
                const int qrow = qw0 + qt * 16 + lc;
                float p[4][4];
#pragma unroll
                for (int kt = 0; kt < 4; ++kt)
#pragma unroll
                    for (int r = 0; r < 4; ++r) {
                        float sv = st[qt][kt][r] * 0.03125f;
                        int kk = kvb + kt * 16 + lg * 4 + r;
                        p[kt][r] = (kk > qrow) ? -1e30f : sv;
                    }
                float mx = p[0][0];
#pragma unroll
                for (int kt = 0; kt < 4; ++kt)
#pragma unroll
                    for (int r = 0; r < 4; ++r) mx = fmaxf(mx, p[kt][r]);
                mx = fmaxf(mx, __shfl_xor(mx, 16, 64));
                mx = fmaxf(mx, __shfl_xor(mx, 32, 64));
                float mnew = fmaxf(m_r[qt], mx);
                float corr = __expf(m_r[qt] - mnew);
                float rs = 0.f;
#pragma unroll
                for (int kt = 0; kt < 4; ++kt)
#pragma unroll
                    for (int r = 0; r < 4; ++r) {
                        p[kt][r] = __expf(p[kt][r] - mnew);
                        rs += p[kt][r];
                    }
                rs += __shfl_xor(rs, 16, 64);
                rs += __shfl_xor(rs, 32, 64);
                l_r[qt] = l_r[qt] * corr + rs;
                m_r[qt] = mnew;
                // rescale O accumulators (row q_local = lg*4+r owned by lane lc==q_local)
                float corr_r[4];
#pragma unroll
                for (int r = 0; r < 4; ++r) corr_r[r] = __shfl(corr, lg * 4 + r, 16);
#pragma unroll
                for (int dt = 0; dt < 4; ++dt)
#pragma unroll
                    for (int r = 0; r < 4; ++r) oacc[qt][dt][r] *= corr_r[r];
                // write P (bf16) to per-wave LDS: Ps[q_local][k_local]
#pragma unroll
                for (int kt = 0; kt < 4; ++kt)
#pragma unroll
                    for (int r = 0; r < 4; ++r)
                        Ps[wave][qt * 16 + lc][kt * 16 + lg * 4 + r] = f2bf(p[kt][r]);
            }
            asm volatile("s_waitcnt lgkmcnt(0)" ::: "memory");

            // ---- O += P V : 16 MFMA ----
            bf16x8 pf[2][2];
#pragma unroll
            for (int qt = 0; qt < 2; ++qt)
#pragma unroll
                for (int c = 0; c < 2; ++c)
                    pf[qt][c] = *(const bf16x8*)&Ps[wave][qt * 16 + lc][c * 32 + lg * 8];
#pragma unroll
            for (int dt = 0; dt < 4; ++dt)
#pragma unroll
                for (int c = 0; c < 2; ++c) {
                    bf16x8 vtf = *(const bf16x8*)&VTs[cur][dt * 16 + lc][((4 * c + lg) ^ lc7) * 8];
#pragma unroll
                    for (int qt = 0; qt < 2; ++qt)
                        oacc[qt][dt] = MFMA16(pf[qt][c], vtf, oacc[qt][dt]);
                }
        }

        // write staged tile kv+1 into the other buffer (no one reads it this iter)
        if (havenext) {
            *(bf16x8*)&Ks[cur ^ 1][srow][swz_a]  = nk0;
            *(bf16x8*)&Ks[cur ^ 1][srow][swz_b]  = nk1;
            *(bf16x8*)&VTs[cur ^ 1][srow][swz_a] = nv0;
            *(bf16x8*)&VTs[cur ^ 1][srow][swz_b] = nv1;
        }
        cur ^= 1;
    }

    // epilogue: normalize, add residual, store
#pragma unroll
    for (int qt = 0; qt < 2; ++qt) {
        float li = 1.0f / l_r[qt];
        float li_r[4];
#pragma unroll
        for (int r = 0; r < 4; ++r) li_r[r] = __shfl(li, lg * 4 + r, 16);
#pragma unroll
        for (int dt = 0; dt < 4; ++dt)
#pragma unroll
            for (int r = 0; r < 4; ++r) {
                int q = qw0 + qt * 16 + lg * 4 + r;
                int dh = dt * 16 + lc;
                size_t oi = ((size_t)b * 2048 + q) * 1024 + (size_t)h * 64 + dh;
                outp[oi] = x[oi] + oacc[qt][dt][r] * li_r[r];
            }
    }
}

extern "C" void kernel_launch(void* const* d_in, const int* in_sizes, int n_in,
                              void* d_out, int out_size, void* d_ws, size_t ws_size,
                              hipStream_t stream) {
    const float* x  = (const float*)d_in[0];
    const float* k  = (const float*)d_in[1];
    const float* v  = (const float*)d_in[2];
    const float* wq = (const float*)d_in[3];
    float* outp = (float*)d_out;

    const size_t NELEM = (size_t)4 * 2048 * 1024;
    unsigned short* qbuf = (unsigned short*)d_ws;
    unsigned short* kbuf = qbuf + NELEM;
    unsigned short* vtbuf = kbuf + NELEM;

    qproj_kernel<<<dim3(64, 8), 256, 0, stream>>>(x, wq, qbuf);
    conv_bf16_kernel<<<(int)(NELEM / 4 / 256), 256, 0, stream>>>(k, kbuf, (int)(NELEM / 4));
    vtrans_kernel<<<dim3(32, 64), 256, 0, stream>>>(v, vtbuf);
    attn_kernel<<<dim3(16, 64), 256, 0, stream>>>(qbuf, kbuf, vtbuf, x, outp);
}

// Round 3
// 152.669 us; speedup vs baseline: 2.5388x; 1.4421x over previous
//
#include <hip/hip_runtime.h>
#include <hip/hip_bf16.h>

// B=4, S=2048, D=1024, H=16, DH=64
typedef __attribute__((ext_vector_type(4))) float f32x4;
typedef __attribute__((ext_vector_type(8))) short bf16x8;
typedef __attribute__((ext_vector_type(4))) unsigned short u16x4;

#define MFMA16(a, b, c) __builtin_amdgcn_mfma_f32_16x16x32_bf16((a), (b), (c), 0, 0, 0)

static __device__ __forceinline__ unsigned short f2bf(float f) {
    unsigned u = __float_as_uint(f);
    u += 0x7FFFu + ((u >> 16) & 1u);   // RNE
    return (unsigned short)(u >> 16);
}

// ---------------- Q projection: q = x @ Wq^T, output bf16 [B,H,S,DH] ----------------
__global__ __launch_bounds__(256) void qproj_kernel(const float* __restrict__ x,
                                                    const float* __restrict__ wq,
                                                    unsigned short* __restrict__ qout) {
    __shared__ __align__(16) unsigned short As[128][40];
    __shared__ __align__(16) unsigned short Bs[128][40];
    const int m0 = blockIdx.x * 128;
    const int n0 = blockIdx.y * 128;
    const int tid = threadIdx.x;
    const int wave = tid >> 6, lane = tid & 63;
    const int lg = lane >> 4, lc = lane & 15;
    const int wm = wave >> 1, wn = wave & 1;

    f32x4 acc[4][4];
#pragma unroll
    for (int i = 0; i < 4; ++i)
#pragma unroll
        for (int j = 0; j < 4; ++j) acc[i][j] = (f32x4){0.f, 0.f, 0.f, 0.f};

    for (int ks = 0; ks < 1024; ks += 32) {
#pragma unroll
        for (int i = 0; i < 4; ++i) {
            int c = tid + i * 256;
            int row = c >> 3, kc = (c & 7) * 4;
            float4 av = *(const float4*)(x + (size_t)(m0 + row) * 1024 + ks + kc);
            u16x4 ab = { f2bf(av.x), f2bf(av.y), f2bf(av.z), f2bf(av.w) };
            *(u16x4*)&As[row][kc] = ab;
            float4 bv = *(const float4*)(wq + (size_t)(n0 + row) * 1024 + ks + kc);
            u16x4 bb = { f2bf(bv.x), f2bf(bv.y), f2bf(bv.z), f2bf(bv.w) };
            *(u16x4*)&Bs[row][kc] = bb;
        }
        __syncthreads();
        bf16x8 af[4], bfr[4];
#pragma unroll
        for (int i = 0; i < 4; ++i) {
            af[i]  = *(const bf16x8*)&As[wm * 64 + i * 16 + lc][lg * 8];
            bfr[i] = *(const bf16x8*)&Bs[wn * 64 + i * 16 + lc][lg * 8];
        }
#pragma unroll
        for (int mi = 0; mi < 4; ++mi)
#pragma unroll
            for (int ni = 0; ni < 4; ++ni)
                acc[mi][ni] = MFMA16(af[mi], bfr[ni], acc[mi][ni]);
        __syncthreads();
    }
#pragma unroll
    for (int mi = 0; mi < 4; ++mi)
#pragma unroll
        for (int ni = 0; ni < 4; ++ni)
#pragma unroll
            for (int r = 0; r < 4; ++r) {
                int m = m0 + wm * 64 + mi * 16 + lg * 4 + r;
                int n = n0 + wn * 64 + ni * 16 + lc;
                int b = m >> 11, s = m & 2047;
                int h = n >> 6, dh = n & 63;
                qout[(((size_t)b * 16 + h) * 2048 + s) * 64 + dh] = f2bf(acc[mi][ni][r]);
            }
}

// ---------------- k fp32 -> bf16 (same layout) ----------------
__global__ void conv_bf16_kernel(const float* __restrict__ in, unsigned short* __restrict__ outp, int n4) {
    int i = blockIdx.x * blockDim.x + threadIdx.x;
    if (i < n4) {
        float4 v = ((const float4*)in)[i];
        u16x4 o = { f2bf(v.x), f2bf(v.y), f2bf(v.z), f2bf(v.w) };
        ((u16x4*)outp)[i] = o;
    }
}

// ---------------- v fp32 [B,H,S,DH] -> bf16 transposed [B,H,DH,S] ----------------
__global__ __launch_bounds__(256) void vtrans_kernel(const float* __restrict__ v, unsigned short* __restrict__ vt) {
    __shared__ float buf[64][65];
    const int s0 = blockIdx.x * 64;
    const int bh = blockIdx.y;
    const int tid = threadIdx.x;
#pragma unroll
    for (int i = 0; i < 4; ++i) {
        int c = tid + i * 256;
        int s = c >> 4, dc = (c & 15) * 4;
        float4 val = *(const float4*)(v + ((size_t)bh * 2048 + s0 + s) * 64 + dc);
        buf[s][dc] = val.x; buf[s][dc + 1] = val.y; buf[s][dc + 2] = val.z; buf[s][dc + 3] = val.w;
    }
    __syncthreads();
#pragma unroll
    for (int i = 0; i < 4; ++i) {
        int c = tid + i * 256;
        int dh = c >> 4, sc = (c & 15) * 4;
        u16x4 o = { f2bf(buf[sc][dh]), f2bf(buf[sc + 1][dh]), f2bf(buf[sc + 2][dh]), f2bf(buf[sc + 3][dh]) };
        *(u16x4*)(vt + ((size_t)bh * 64 + dh) * 2048 + s0 + sc) = o;
    }
}

// ---------------- fused causal flash attention + residual ----------------
// grid: (8, B*H). Each block handles TWO q-blocks (qb=p and qb=15-p) sequentially
// -> uniform 34 iterations/block, 512 blocks all-resident (no causal tail).
// Swapped QK^T (S^T = K Q^T) AND swapped PV (O^T = V^T P^T): all softmax state
// lives in the col=q-row=lc domain -> zero shuffles for rescale/normalize.
__global__ __launch_bounds__(256) void attn_kernel(const unsigned short* __restrict__ qg,
                                                   const unsigned short* __restrict__ kg,
                                                   const unsigned short* __restrict__ vtg,
                                                   const float* __restrict__ x,
                                                   float* __restrict__ outp) {
    __shared__ __align__(16) unsigned short Ks[2][64][64];
    __shared__ __align__(16) unsigned short VTs[2][64][64];
    __shared__ __align__(16) unsigned short Ps[4][32][72];

    const int pr = blockIdx.x;          // pair index 0..7
    const int bh = blockIdx.y;
    const int b = bh >> 4, h = bh & 15;
    const int tid = threadIdx.x;
    const int wave = tid >> 6, lane = tid & 63;
    const int lg = lane >> 4, lc = lane & 15;
    const int lc7 = lc & 7;

    // staging coords: thread -> row (0..63), two 8-elem chunks at (tid&3)*16
    const int srow = tid >> 2;
    const int scb  = (tid & 3) * 16;
    const int c16a = (tid & 3) * 2;
    const int swz_a = (c16a ^ (srow & 7)) * 8;
    const int swz_b = ((c16a + 1) ^ (srow & 7)) * 8;
    const unsigned short* kbase = kg  + ((size_t)bh * 2048 + srow) * 64 + scb;
    const unsigned short* vbase = vtg + ((size_t)bh * 64 + srow) * 2048 + scb;

    for (int seg = 0; seg < 2; ++seg) {
        const int qb = seg ? (15 - pr) : pr;
        const int qw0 = qb * 128 + wave * 32;
        const int nkv = 2 * qb + 2;

        // Q B-frags in registers: qf[qt][c] = Q[qw0+qt*16+lc][c*32 + lg*8 ..]
        bf16x8 qf[2][2];
#pragma unroll
        for (int qt = 0; qt < 2; ++qt)
#pragma unroll
            for (int c = 0; c < 2; ++c)
                qf[qt][c] = *(const bf16x8*)(qg + ((size_t)bh * 2048 + qw0 + qt * 16 + lc) * 64 + c * 32 + lg * 8);

        f32x4 oacc[2][4];   // O^T: oacc[qt][dt], col=lc=q-local, row=lg*4+r=dh-local
#pragma unroll
        for (int qt = 0; qt < 2; ++qt)
#pragma unroll
            for (int dt = 0; dt < 4; ++dt) oacc[qt][dt] = (f32x4){0.f, 0.f, 0.f, 0.f};
        float m_r[2] = {-1e30f, -1e30f};
        float l_r[2] = {0.f, 0.f};

        if (seg) __syncthreads();   // protect buffer reuse across segments

        // prologue: stage tile 0 into buffer 0
        {
            bf16x8 k0 = *(const bf16x8*)(kbase);
            bf16x8 k1 = *(const bf16x8*)(kbase + 8);
            bf16x8 v0 = *(const bf16x8*)(vbase);
            bf16x8 v1 = *(const bf16x8*)(vbase + 8);
            *(bf16x8*)&Ks[0][srow][swz_a]  = k0;
            *(bf16x8*)&Ks[0][srow][swz_b]  = k1;
            *(bf16x8*)&VTs[0][srow][swz_a] = v0;
            *(bf16x8*)&VTs[0][srow][swz_b] = v1;
        }

        int cur = 0;
        for (int kv = 0; kv < nkv; ++kv) {
            __syncthreads();

            // issue next-tile global loads (latency hides under compute)
            const bool havenext = (kv + 1 < nkv);
            const int nxt = havenext ? kv + 1 : kv;
            bf16x8 nk0 = *(const bf16x8*)(kbase + (size_t)nxt * 4096);
            bf16x8 nk1 = *(const bf16x8*)(kbase + (size_t)nxt * 4096 + 8);
            bf16x8 nv0 = *(const bf16x8*)(vbase + nxt * 64);
            bf16x8 nv1 = *(const bf16x8*)(vbase + nxt * 64 + 8);

            const bool active = (kv * 64 <= qw0 + 31);
            if (active) {
                // ---- S^T = K Q^T : 16 MFMA ----
                bf16x8 kf[4][2];
#pragma unroll
                for (int kt = 0; kt < 4; ++kt)
#pragma unroll
                    for (int c = 0; c < 2; ++c)
                        kf[kt][c] = *(const bf16x8*)&Ks[cur][kt * 16 + lc][((4 * c + lg) ^ lc7) * 8];

                f32x4 st[2][4];
                __builtin_amdgcn_s_setprio(1);
#pragma unroll
                for (int qt = 0; qt < 2; ++qt)
#pragma unroll
                    for (int kt = 0; kt < 4; ++kt) {
                        f32x4 a = (f32x4){0.f, 0.f, 0.f, 0.f};
                        a = MFMA16(kf[kt][0], qf[qt][0], a);
                        a = MFMA16(kf[kt][1], qf[qt][1], a);
                        st[qt][kt] = a;
                    }
                __builtin_amdgcn_s_setprio(0);

                const int kvb = kv * 64;
                // ---- softmax: q-row = qw0+qt*16+lc; scores+stats all in col=lc domain ----
#pragma unroll
                for (int qt = 0; qt < 2; ++qt) {
                    const int qrow = qw0 + qt * 16 + lc;
                    float p[4][4];
#pragma unroll
                    for (int kt = 0; kt < 4; ++kt)
#pragma unroll
                        for (int r = 0; r < 4; ++r) {
                            float sv = st[qt][kt][r] * 0.03125f;
                            int kk = kvb + kt * 16 + lg * 4 + r;
                            p[kt][r] = (kk > qrow) ? -1e30f : sv;
                        }
                    float mx = p[0][0];
#pragma unroll
                    for (int kt = 0; kt < 4; ++kt)
#pragma unroll
                        for (int r = 0; r < 4; ++r) mx = fmaxf(mx, p[kt][r]);
                    mx = fmaxf(mx, __shfl_xor(mx, 16, 64));
                    mx = fmaxf(mx, __shfl_xor(mx, 32, 64));
                    float mnew = fmaxf(m_r[qt], mx);
                    float corr = __expf(m_r[qt] - mnew);
                    float rs = 0.f;
#pragma unroll
                    for (int kt = 0; kt < 4; ++kt)
#pragma unroll
                        for (int r = 0; r < 4; ++r) {
                            p[kt][r] = __expf(p[kt][r] - mnew);
                            rs += p[kt][r];
                        }
                    rs += __shfl_xor(rs, 16, 64);
                    rs += __shfl_xor(rs, 32, 64);
                    l_r[qt] = l_r[qt] * corr + rs;
                    m_r[qt] = mnew;
                    // O^T rescale: col=lc owns q-row -> plain per-lane multiply
#pragma unroll
                    for (int dt = 0; dt < 4; ++dt)
#pragma unroll
                        for (int r = 0; r < 4; ++r) oacc[qt][dt][r] *= corr;
                    // write P (bf16, vectorized b64) to per-wave LDS: Ps[q_local][k_local]
#pragma unroll
                    for (int kt = 0; kt < 4; ++kt) {
                        u16x4 w = { f2bf(p[kt][0]), f2bf(p[kt][1]), f2bf(p[kt][2]), f2bf(p[kt][3]) };
                        *(u16x4*)&Ps[wave][qt * 16 + lc][kt * 16 + lg * 4] = w;
                    }
                }
                asm volatile("s_waitcnt lgkmcnt(0)" ::: "memory");

                // ---- O^T += V^T P^T : 16 MFMA (A=V^T frag, B=P frag) ----
                bf16x8 pf[2][2];
#pragma unroll
                for (int qt = 0; qt < 2; ++qt)
#pragma unroll
                    for (int c = 0; c < 2; ++c)
                        pf[qt][c] = *(const bf16x8*)&Ps[wave][qt * 16 + lc][c * 32 + lg * 8];
                __builtin_amdgcn_s_setprio(1);
#pragma unroll
                for (int dt = 0; dt < 4; ++dt)
#pragma unroll
                    for (int c = 0; c < 2; ++c) {
                        bf16x8 vtf = *(const bf16x8*)&VTs[cur][dt * 16 + lc][((4 * c + lg) ^ lc7) * 8];
#pragma unroll
                        for (int qt = 0; qt < 2; ++qt)
                            oacc[qt][dt] = MFMA16(vtf, pf[qt][c], oacc[qt][dt]);
                    }
                __builtin_amdgcn_s_setprio(0);
            }

            // write staged tile kv+1 into the other buffer
            if (havenext) {
                *(bf16x8*)&Ks[cur ^ 1][srow][swz_a]  = nk0;
                *(bf16x8*)&Ks[cur ^ 1][srow][swz_b]  = nk1;
                *(bf16x8*)&VTs[cur ^ 1][srow][swz_a] = nv0;
                *(bf16x8*)&VTs[cur ^ 1][srow][swz_b] = nv1;
            }
            cur ^= 1;
        }

        // epilogue: normalize (per-lane), add residual, store O^T scatter (L2 merges)
#pragma unroll
        for (int qt = 0; qt < 2; ++qt) {
            float li = 1.0f / l_r[qt];
            const int q = qw0 + qt * 16 + lc;
#pragma unroll
            for (int dt = 0; dt < 4; ++dt)
#pragma unroll
                for (int r = 0; r < 4; ++r) {
                    int dh = dt * 16 + lg * 4 + r;
                    size_t oi = ((size_t)b * 2048 + q) * 1024 + (size_t)h * 64 + dh;
                    outp[oi] = x[oi] + oacc[qt][dt][r] * li;
                }
        }
    }
}

extern "C" void kernel_launch(void* const* d_in, const int* in_sizes, int n_in,
                              void* d_out, int out_size, void* d_ws, size_t ws_size,
                              hipStream_t stream) {
    const float* x  = (const float*)d_in[0];
    const float* k  = (const float*)d_in[1];
    const float* v  = (const float*)d_in[2];
    const float* wq = (const float*)d_in[3];
    float* outp = (float*)d_out;

    const size_t NELEM = (size_t)4 * 2048 * 1024;
    unsigned short* qbuf = (unsigned short*)d_ws;
    unsigned short* kbuf = qbuf + NELEM;
    unsigned short* vtbuf = kbuf + NELEM;

    qproj_kernel<<<dim3(64, 8), 256, 0, stream>>>(x, wq, qbuf);
    conv_bf16_kernel<<<(int)(NELEM / 4 / 256), 256, 0, stream>>>(k, kbuf, (int)(NELEM / 4));
    vtrans_kernel<<<dim3(32, 64), 256, 0, stream>>>(v, vtbuf);
    attn_kernel<<<dim3(8, 64), 256, 0, stream>>>(qbuf, kbuf, vtbuf, x, outp);
}

// Round 4
// 136.608 us; speedup vs baseline: 2.8373x; 1.1176x over previous
//
#include <hip/hip_runtime.h>
#include <hip/hip_bf16.h>

// B=4, S=2048, D=1024, H=16, DH=64
typedef __attribute__((ext_vector_type(4))) float f32x4;
typedef __attribute__((ext_vector_type(8))) short bf16x8;
typedef __attribute__((ext_vector_type(4))) unsigned short u16x4;

#define MFMA16(a, b, c) __builtin_amdgcn_mfma_f32_16x16x32_bf16((a), (b), (c), 0, 0, 0)

static __device__ __forceinline__ unsigned short f2bf(float f) {
    unsigned u = __float_as_uint(f);
    u += 0x7FFFu + ((u >> 16) & 1u);   // RNE
    return (unsigned short)(u >> 16);
}
// round-half-up: fine for non-negative P values, 2 VALU ops
static __device__ __forceinline__ unsigned short f2bf_ru(float f) {
    return (unsigned short)((__float_as_uint(f) + 0x8000u) >> 16);
}
static __device__ __forceinline__ float exp2_fast(float x) {
#if __has_builtin(__builtin_amdgcn_exp2f)
    return __builtin_amdgcn_exp2f(x);
#else
    return exp2f(x);
#endif
}

// scores premultiplied so softmax runs in exp2 domain: c = log2(e)/32
#define QSCALE 0.04508422002778011f

// ---------------- Q projection: q = (x @ Wq^T) * QSCALE, bf16 [B,H,S,DH] ----------------
__global__ __launch_bounds__(256) void qproj_kernel(const float* __restrict__ x,
                                                    const float* __restrict__ wq,
                                                    unsigned short* __restrict__ qout) {
    __shared__ __align__(16) unsigned short As[128][40];
    __shared__ __align__(16) unsigned short Bs[128][40];
    const int m0 = blockIdx.x * 128;
    const int n0 = blockIdx.y * 128;
    const int tid = threadIdx.x;
    const int wave = tid >> 6, lane = tid & 63;
    const int lg = lane >> 4, lc = lane & 15;
    const int wm = wave >> 1, wn = wave & 1;

    f32x4 acc[4][4];
#pragma unroll
    for (int i = 0; i < 4; ++i)
#pragma unroll
        for (int j = 0; j < 4; ++j) acc[i][j] = (f32x4){0.f, 0.f, 0.f, 0.f};

    for (int ks = 0; ks < 1024; ks += 32) {
#pragma unroll
        for (int i = 0; i < 4; ++i) {
            int c = tid + i * 256;
            int row = c >> 3, kc = (c & 7) * 4;
            float4 av = *(const float4*)(x + (size_t)(m0 + row) * 1024 + ks + kc);
            u16x4 ab = { f2bf(av.x), f2bf(av.y), f2bf(av.z), f2bf(av.w) };
            *(u16x4*)&As[row][kc] = ab;
            float4 bv = *(const float4*)(wq + (size_t)(n0 + row) * 1024 + ks + kc);
            u16x4 bb = { f2bf(bv.x), f2bf(bv.y), f2bf(bv.z), f2bf(bv.w) };
            *(u16x4*)&Bs[row][kc] = bb;
        }
        __syncthreads();
        bf16x8 af[4], bfr[4];
#pragma unroll
        for (int i = 0; i < 4; ++i) {
            af[i]  = *(const bf16x8*)&As[wm * 64 + i * 16 + lc][lg * 8];
            bfr[i] = *(const bf16x8*)&Bs[wn * 64 + i * 16 + lc][lg * 8];
        }
#pragma unroll
        for (int mi = 0; mi < 4; ++mi)
#pragma unroll
            for (int ni = 0; ni < 4; ++ni)
                acc[mi][ni] = MFMA16(af[mi], bfr[ni], acc[mi][ni]);
        __syncthreads();
    }
#pragma unroll
    for (int mi = 0; mi < 4; ++mi)
#pragma unroll
        for (int ni = 0; ni < 4; ++ni)
#pragma unroll
            for (int r = 0; r < 4; ++r) {
                int m = m0 + wm * 64 + mi * 16 + lg * 4 + r;
                int n = n0 + wn * 64 + ni * 16 + lc;
                int b = m >> 11, s = m & 2047;
                int h = n >> 6, dh = n & 63;
                qout[(((size_t)b * 16 + h) * 2048 + s) * 64 + dh] = f2bf(acc[mi][ni][r] * QSCALE);
            }
}

// ---------------- fused: k fp32->bf16  AND  v fp32 [B,H,S,DH] -> bf16 [B,H,DH,S] ----------------
__global__ __launch_bounds__(256) void convtrans_kernel(const float* __restrict__ kin,
                                                        const float* __restrict__ vin,
                                                        unsigned short* __restrict__ kb,
                                                        unsigned short* __restrict__ vt) {
    __shared__ float buf[64][65];
    const int bid = blockIdx.x;
    const int tid = threadIdx.x;
    if (bid < 8192) {                  // k conversion: 8192 blocks x 256 thr x 4 elem
        int i = bid * 256 + tid;
        float4 v = ((const float4*)kin)[i];
        u16x4 o = { f2bf(v.x), f2bf(v.y), f2bf(v.z), f2bf(v.w) };
        ((u16x4*)kb)[i] = o;
    } else {                           // v transpose: 2048 blocks
        const int idx = bid - 8192;
        const int s0 = (idx & 31) * 64;
        const int bh = idx >> 5;
#pragma unroll
        for (int i = 0; i < 4; ++i) {
            int c = tid + i * 256;
            int s = c >> 4, dc = (c & 15) * 4;
            float4 val = *(const float4*)(vin + ((size_t)bh * 2048 + s0 + s) * 64 + dc);
            buf[s][dc] = val.x; buf[s][dc + 1] = val.y; buf[s][dc + 2] = val.z; buf[s][dc + 3] = val.w;
        }
        __syncthreads();
#pragma unroll
        for (int i = 0; i < 4; ++i) {
            int c = tid + i * 256;
            int dh = c >> 4, sc = (c & 15) * 4;
            u16x4 o = { f2bf(buf[sc][dh]), f2bf(buf[sc + 1][dh]), f2bf(buf[sc + 2][dh]), f2bf(buf[sc + 3][dh]) };
            *(u16x4*)(vt + ((size_t)bh * 64 + dh) * 2048 + s0 + sc) = o;
        }
    }
}

// ---------------- fused causal flash attention + residual ----------------
// grid: (8, B*H). Each block handles qb=p and qb=15-p -> uniform 34 iters, 512 blocks.
// Swapped QK^T and swapped PV: softmax state in col=q=lc domain, no shuffles for rescale.
// exp2-domain scores (scale folded into Q), diagonal-only masking, defer-max (THR=8).
__global__ __launch_bounds__(256) void attn_kernel(const unsigned short* __restrict__ qg,
                                                   const unsigned short* __restrict__ kg,
                                                   const unsigned short* __restrict__ vtg,
                                                   const float* __restrict__ x,
                                                   float* __restrict__ outp) {
    __shared__ __align__(16) unsigned short Ks[2][64][64];
    __shared__ __align__(16) unsigned short VTs[2][64][64];
    __shared__ __align__(16) unsigned short Ps[4][32][72];

    const int pr = blockIdx.x;
    const int bh = blockIdx.y;
    const int b = bh >> 4, h = bh & 15;
    const int tid = threadIdx.x;
    const int wave = tid >> 6, lane = tid & 63;
    const int lg = lane >> 4, lc = lane & 15;
    const int lc7 = lc & 7;

    const int srow = tid >> 2;
    const int scb  = (tid & 3) * 16;
    const int c16a = (tid & 3) * 2;
    const int swz_a = (c16a ^ (srow & 7)) * 8;
    const int swz_b = ((c16a + 1) ^ (srow & 7)) * 8;
    const unsigned short* kbase = kg  + ((size_t)bh * 2048 + srow) * 64 + scb;
    const unsigned short* vbase = vtg + ((size_t)bh * 64 + srow) * 2048 + scb;

    for (int seg = 0; seg < 2; ++seg) {
        const int qb = seg ? (15 - pr) : pr;
        const int qw0 = qb * 128 + wave * 32;
        const int nkv = 2 * qb + 2;

        bf16x8 qf[2][2];
#pragma unroll
        for (int qt = 0; qt < 2; ++qt)
#pragma unroll
            for (int c = 0; c < 2; ++c)
                qf[qt][c] = *(const bf16x8*)(qg + ((size_t)bh * 2048 + qw0 + qt * 16 + lc) * 64 + c * 32 + lg * 8);

        f32x4 oacc[2][4];   // O^T: col=lc=q-local, row=lg*4+r=dh-local
#pragma unroll
        for (int qt = 0; qt < 2; ++qt)
#pragma unroll
            for (int dt = 0; dt < 4; ++dt) oacc[qt][dt] = (f32x4){0.f, 0.f, 0.f, 0.f};
        float m_r[2] = {-1e30f, -1e30f};
        float l_r[2] = {0.f, 0.f};

        if (seg) __syncthreads();

        {   // prologue: stage tile 0 into buffer 0
            bf16x8 k0 = *(const bf16x8*)(kbase);
            bf16x8 k1 = *(const bf16x8*)(kbase + 8);
            bf16x8 v0 = *(const bf16x8*)(vbase);
            bf16x8 v1 = *(const bf16x8*)(vbase + 8);
            *(bf16x8*)&Ks[0][srow][swz_a]  = k0;
            *(bf16x8*)&Ks[0][srow][swz_b]  = k1;
            *(bf16x8*)&VTs[0][srow][swz_a] = v0;
            *(bf16x8*)&VTs[0][srow][swz_b] = v1;
        }

        int cur = 0;
        for (int kv = 0; kv < nkv; ++kv) {
            __syncthreads();

            const bool havenext = (kv + 1 < nkv);
            const int nxt = havenext ? kv + 1 : kv;
            bf16x8 nk0 = *(const bf16x8*)(kbase + (size_t)nxt * 4096);
            bf16x8 nk1 = *(const bf16x8*)(kbase + (size_t)nxt * 4096 + 8);
            bf16x8 nv0 = *(const bf16x8*)(vbase + nxt * 64);
            bf16x8 nv1 = *(const bf16x8*)(vbase + nxt * 64 + 8);

            const bool active = (kv * 64 <= qw0 + 31);
            if (active) {
                // ---- S^T = K Q^T : 16 MFMA ----
                bf16x8 kf[4][2];
#pragma unroll
                for (int kt = 0; kt < 4; ++kt)
#pragma unroll
                    for (int c = 0; c < 2; ++c)
                        kf[kt][c] = *(const bf16x8*)&Ks[cur][kt * 16 + lc][((4 * c + lg) ^ lc7) * 8];

                f32x4 st[2][4];
                __builtin_amdgcn_s_setprio(1);
#pragma unroll
                for (int qt = 0; qt < 2; ++qt)
#pragma unroll
                    for (int kt = 0; kt < 4; ++kt) {
                        f32x4 a = (f32x4){0.f, 0.f, 0.f, 0.f};
                        a = MFMA16(kf[kt][0], qf[qt][0], a);
                        a = MFMA16(kf[kt][1], qf[qt][1], a);
                        st[qt][kt] = a;
                    }
                __builtin_amdgcn_s_setprio(0);

                const int kvb = kv * 64;
#pragma unroll
                for (int qt = 0; qt < 2; ++qt) {
                    const int qrow = qw0 + qt * 16 + lc;
                    float p[4][4];
#pragma unroll
                    for (int kt = 0; kt < 4; ++kt)
#pragma unroll
                        for (int r = 0; r < 4; ++r) p[kt][r] = st[qt][kt][r];
                    if (kvb + 63 > qw0 + qt * 16) {   // diagonal tile only (wave-uniform)
#pragma unroll
                        for (int kt = 0; kt < 4; ++kt)
#pragma unroll
                            for (int r = 0; r < 4; ++r) {
                                int kk = kvb + kt * 16 + lg * 4 + r;
                                if (kk > qrow) p[kt][r] = -1e30f;
                            }
                    }
                    float mx = p[0][0];
#pragma unroll
                    for (int kt = 0; kt < 4; ++kt)
#pragma unroll
                        for (int r = 0; r < 4; ++r) mx = fmaxf(mx, p[kt][r]);
                    mx = fmaxf(mx, __shfl_xor(mx, 16, 64));
                    mx = fmaxf(mx, __shfl_xor(mx, 32, 64));
                    // defer-max: only rescale when max grew by > 8 (exp2 domain)
                    if (!__all(mx <= m_r[qt] + 8.0f)) {
                        float mnew = fmaxf(m_r[qt], mx);
                        float corr = exp2_fast(m_r[qt] - mnew);
                        m_r[qt] = mnew;
                        l_r[qt] *= corr;
#pragma unroll
                        for (int dt = 0; dt < 4; ++dt)
#pragma unroll
                            for (int r = 0; r < 4; ++r) oacc[qt][dt][r] *= corr;
                    }
                    const float m2 = m_r[qt];
                    float rs = 0.f;
#pragma unroll
                    for (int kt = 0; kt < 4; ++kt)
#pragma unroll
                        for (int r = 0; r < 4; ++r) {
                            float e = exp2_fast(p[kt][r] - m2);
                            p[kt][r] = e;
                            rs += e;
                        }
                    rs += __shfl_xor(rs, 16, 64);
                    rs += __shfl_xor(rs, 32, 64);
                    l_r[qt] += rs;
#pragma unroll
                    for (int kt = 0; kt < 4; ++kt) {
                        u16x4 w = { f2bf_ru(p[kt][0]), f2bf_ru(p[kt][1]), f2bf_ru(p[kt][2]), f2bf_ru(p[kt][3]) };
                        *(u16x4*)&Ps[wave][qt * 16 + lc][kt * 16 + lg * 4] = w;
                    }
                }
                asm volatile("s_waitcnt lgkmcnt(0)" ::: "memory");

                // ---- O^T += V^T P^T : 16 MFMA ----
                bf16x8 pf[2][2];
#pragma unroll
                for (int qt = 0; qt < 2; ++qt)
#pragma unroll
                    for (int c = 0; c < 2; ++c)
                        pf[qt][c] = *(const bf16x8*)&Ps[wave][qt * 16 + lc][c * 32 + lg * 8];
                __builtin_amdgcn_s_setprio(1);
#pragma unroll
                for (int dt = 0; dt < 4; ++dt)
#pragma unroll
                    for (int c = 0; c < 2; ++c) {
                        bf16x8 vtf = *(const bf16x8*)&VTs[cur][dt * 16 + lc][((4 * c + lg) ^ lc7) * 8];
#pragma unroll
                        for (int qt = 0; qt < 2; ++qt)
                            oacc[qt][dt] = MFMA16(vtf, pf[qt][c], oacc[qt][dt]);
                    }
                __builtin_amdgcn_s_setprio(0);
            }

            if (havenext) {
                *(bf16x8*)&Ks[cur ^ 1][srow][swz_a]  = nk0;
                *(bf16x8*)&Ks[cur ^ 1][srow][swz_b]  = nk1;
                *(bf16x8*)&VTs[cur ^ 1][srow][swz_a] = nv0;
                *(bf16x8*)&VTs[cur ^ 1][srow][swz_b] = nv1;
            }
            cur ^= 1;
        }

        // epilogue: normalize (per-lane), add residual, store O^T scatter (L2 merges)
#pragma unroll
        for (int qt = 0; qt < 2; ++qt) {
            float li = 1.0f / l_r[qt];
            const int q = qw0 + qt * 16 + lc;
#pragma unroll
            for (int dt = 0; dt < 4; ++dt)
#pragma unroll
                for (int r = 0; r < 4; ++r) {
                    int dh = dt * 16 + lg * 4 + r;
                    size_t oi = ((size_t)b * 2048 + q) * 1024 + (size_t)h * 64 + dh;
                    outp[oi] = x[oi] + oacc[qt][dt][r] * li;
                }
        }
    }
}

extern "C" void kernel_launch(void* const* d_in, const int* in_sizes, int n_in,
                              void* d_out, int out_size, void* d_ws, size_t ws_size,
                              hipStream_t stream) {
    const float* x  = (const float*)d_in[0];
    const float* k  = (const float*)d_in[1];
    const float* v  = (const float*)d_in[2];
    const float* wq = (const float*)d_in[3];
    float* outp = (float*)d_out;

    const size_t NELEM = (size_t)4 * 2048 * 1024;
    unsigned short* qbuf = (unsigned short*)d_ws;
    unsigned short* kbuf = qbuf + NELEM;
    unsigned short* vtbuf = kbuf + NELEM;

    qproj_kernel<<<dim3(64, 8), 256, 0, stream>>>(x, wq, qbuf);
    convtrans_kernel<<<8192 + 2048, 256, 0, stream>>>(k, v, kbuf, vtbuf);
    attn_kernel<<<dim3(8, 64), 256, 0, stream>>>(qbuf, kbuf, vtbuf, x, outp);
}